// Round 1
// baseline (714.442 us; speedup 1.0000x reference)
//
#include <hip/hip_runtime.h>

using u16 = unsigned short;
typedef short bf16x8 __attribute__((ext_vector_type(8)));
typedef float f32x4 __attribute__((ext_vector_type(4)));

#define NTOK 2048
#define DMODEL 1024
#define NHEAD 16
#define DHEAD 64
#define ATTN_ELEMS (NHEAD * NTOK * NTOK)  // 67108864

__device__ __forceinline__ u16 f2bf(float f) {
    union { float f; unsigned u; } v; v.f = f;
    unsigned r = v.u + 0x7fffu + ((v.u >> 16) & 1u);
    return (u16)(r >> 16);
}

struct GemmArgs {
    const void* A[3];
    const float* W[3];
    const float* bias[3];
    void* C[3];
};

// C[M,N] = A[M,K] @ W[K,N] + bias.  128x128 tile, BK=32, 256 threads (4 waves 2x2).
// A is fp32 (converted to bf16 in staging) or bf16; W fp32 -> bf16 staged transposed.
template <bool A_F32, bool OUT_F32>
__global__ __launch_bounds__(256)
void gemm_bias_k(GemmArgs ga, int M, int N, int K)
{
    __shared__ u16 As[128][40];   // +8 pad: 2-way bank alias only (free)
    __shared__ u16 Wt[128][40];   // W tile stored TRANSPOSED: Wt[col][k]
    const void*  Ap   = ga.A[blockIdx.z];
    const float* W    = ga.W[blockIdx.z];
    const float* bias = ga.bias[blockIdx.z];
    void*        Cp   = ga.C[blockIdx.z];

    const int tid = threadIdx.x;
    const int m0 = blockIdx.y * 128;
    const int n0 = blockIdx.x * 128;
    const int w = tid >> 6, l = tid & 63;
    const int wm = (w >> 1) * 64, wn = (w & 1) * 64;
    const int lr = l & 15, lg = l >> 4;

    f32x4 acc[4][4] = {};

    for (int kb = 0; kb < K; kb += 32) {
        if (A_F32) {
            const float* A = (const float*)Ap;
            #pragma unroll
            for (int i = 0; i < 4; i++) {
                int idx = tid + i * 256;           // 0..1023
                int row = idx >> 3, kc = (idx & 7) * 4;
                float4 f = *(const float4*)(A + (size_t)(m0 + row) * K + kb + kc);
                As[row][kc + 0] = f2bf(f.x);
                As[row][kc + 1] = f2bf(f.y);
                As[row][kc + 2] = f2bf(f.z);
                As[row][kc + 3] = f2bf(f.w);
            }
        } else {
            const u16* A = (const u16*)Ap;
            #pragma unroll
            for (int i = 0; i < 2; i++) {
                int idx = tid + i * 256;           // 0..511
                int row = idx >> 2, kc = (idx & 3) * 8;
                *(bf16x8*)&As[row][kc] =
                    *(const bf16x8*)(A + (size_t)(m0 + row) * K + kb + kc);
            }
        }
        // stage W transposed
        #pragma unroll
        for (int i = 0; i < 4; i++) {
            int idx = tid + i * 256;               // 0..1023
            int r  = idx >> 5;                     // k-row 0..31
            int nc = (idx & 31) * 4;               // col 0..127
            float4 f = *(const float4*)(W + (size_t)(kb + r) * N + n0 + nc);
            Wt[nc + 0][r] = f2bf(f.x);
            Wt[nc + 1][r] = f2bf(f.y);
            Wt[nc + 2][r] = f2bf(f.z);
            Wt[nc + 3][r] = f2bf(f.w);
        }
        __syncthreads();

        bf16x8 a[4], b[4];
        #pragma unroll
        for (int fm = 0; fm < 4; fm++) a[fm] = *(const bf16x8*)&As[wm + fm * 16 + lr][lg * 8];
        #pragma unroll
        for (int fn = 0; fn < 4; fn++) b[fn] = *(const bf16x8*)&Wt[wn + fn * 16 + lr][lg * 8];
        #pragma unroll
        for (int fm = 0; fm < 4; fm++)
            #pragma unroll
            for (int fn = 0; fn < 4; fn++)
                acc[fm][fn] = __builtin_amdgcn_mfma_f32_16x16x32_bf16(a[fm], b[fn], acc[fm][fn], 0, 0, 0);
        __syncthreads();
    }

    #pragma unroll
    for (int fm = 0; fm < 4; fm++)
        #pragma unroll
        for (int fn = 0; fn < 4; fn++) {
            int col = n0 + wn + fn * 16 + lr;
            float bv = bias[col];
            #pragma unroll
            for (int i = 0; i < 4; i++) {
                int row = m0 + wm + fm * 16 + lg * 4 + i;
                float v = acc[fm][fn][i] + bv;
                if (OUT_F32) ((float*)Cp)[(size_t)row * N + col] = v;
                else         ((u16*)Cp)[(size_t)row * N + col] = f2bf(v);
            }
        }
}

// VhT[h][d][n] = Vb[n][h*64+d]   (bf16), 64x64 LDS tile transpose
__global__ __launch_bounds__(256)
void transpose_v_k(const u16* __restrict__ Vb, u16* __restrict__ VhT)
{
    __shared__ u16 tile[64][65];
    const int h = blockIdx.y;
    const int nb = blockIdx.x * 64;
    const int t = threadIdx.x;
    #pragma unroll
    for (int i = 0; i < 16; i++) {
        int idx = i * 256 + t;        // 0..4095
        int nl = idx >> 6, d = idx & 63;
        tile[nl][d] = Vb[(size_t)(nb + nl) * DMODEL + h * 64 + d];
    }
    __syncthreads();
    #pragma unroll
    for (int i = 0; i < 16; i++) {
        int idx = i * 256 + t;
        int d = idx >> 6, nl = idx & 63;
        VhT[(size_t)h * (DHEAD * NTOK) + (size_t)d * NTOK + nb + nl] = tile[nl][d];
    }
}

// u[h,q,k] = dot(Qh[q,:], Kh[k,:]) / 8  -> fp32 into d_out attn region (scratch)
__global__ __launch_bounds__(256)
void scores_k(const u16* __restrict__ Qb, const u16* __restrict__ Kb, float* __restrict__ u)
{
    const int h = blockIdx.z;
    const int q0 = blockIdx.y * 128, k0 = blockIdx.x * 128;
    const int tid = threadIdx.x, w = tid >> 6, l = tid & 63;
    const int wq = (w >> 1) * 64, wk = (w & 1) * 64;
    const int lr = l & 15, lg = l >> 4;
    const u16* Qh = Qb + h * 64;
    const u16* Kh = Kb + h * 64;

    f32x4 acc[4][4] = {};
    #pragma unroll
    for (int d = 0; d < 64; d += 32) {
        bf16x8 a[4], b[4];
        int dk = d + lg * 8;
        #pragma unroll
        for (int fm = 0; fm < 4; fm++)
            a[fm] = *(const bf16x8*)(Qh + (size_t)(q0 + wq + fm * 16 + lr) * DMODEL + dk);
        #pragma unroll
        for (int fn = 0; fn < 4; fn++)
            b[fn] = *(const bf16x8*)(Kh + (size_t)(k0 + wk + fn * 16 + lr) * DMODEL + dk);
        #pragma unroll
        for (int fm = 0; fm < 4; fm++)
            #pragma unroll
            for (int fn = 0; fn < 4; fn++)
                acc[fm][fn] = __builtin_amdgcn_mfma_f32_16x16x32_bf16(a[fm], b[fn], acc[fm][fn], 0, 0, 0);
    }
    float* uh = u + (size_t)h * (NTOK * NTOK);
    #pragma unroll
    for (int fm = 0; fm < 4; fm++)
        #pragma unroll
        for (int fn = 0; fn < 4; fn++)
            #pragma unroll
            for (int i = 0; i < 4; i++)
                uh[(size_t)(q0 + wq + fm * 16 + lg * 4 + i) * NTOK + k0 + wk + fn * 16 + lr] =
                    acc[fm][fn][i] * 0.125f;
}

// Column (query-axis) softmax partials over 256-row chunks: pm/pl[qc][h][k]
__global__ __launch_bounds__(256)
void colpart_k(const float* __restrict__ u, float* __restrict__ pm, float* __restrict__ pl)
{
    const int h = blockIdx.z, qc = blockIdx.y;
    const int k = blockIdx.x * 256 + threadIdx.x;
    const float* col = u + (size_t)h * (NTOK * NTOK) + (size_t)qc * 256 * NTOK + k;
    float m = -1e30f, s = 0.f;
    for (int q = 0; q < 256; q++) {
        float x = col[(size_t)q * NTOK];
        float m2 = fmaxf(m, x);
        s = s * __expf(m - m2) + __expf(x - m2);
        m = m2;
    }
    size_t idx = ((size_t)qc * NHEAD + h) * NTOK + k;
    pm[idx] = m;
    pl[idx] = s;
}

__global__ __launch_bounds__(256)
void colreduce_k(const float* __restrict__ pm, const float* __restrict__ pl,
                 float* __restrict__ mbuf, float* __restrict__ rbuf)
{
    const int h = blockIdx.y;
    const int k = blockIdx.x * 256 + threadIdx.x;
    float m = -1e30f;
    #pragma unroll
    for (int qc = 0; qc < 8; qc++)
        m = fmaxf(m, pm[((size_t)qc * NHEAD + h) * NTOK + k]);
    float lsum = 0.f;
    #pragma unroll
    for (int qc = 0; qc < 8; qc++) {
        size_t idx = ((size_t)qc * NHEAD + h) * NTOK + k;
        lsum += pl[idx] * __expf(pm[idx] - m);
    }
    mbuf[h * NTOK + k] = m;
    rbuf[h * NTOK + k] = 1.0f / lsum;
}

// attn = exp(u - m[k]) * r[k]  (written back in place over u),
// OH[h][q][d] += attn @ Vh     (bf16 out for the final GEMM)
__global__ __launch_bounds__(256)
void pv_k(float* __restrict__ u, const u16* __restrict__ VhT,
          const float* __restrict__ mbuf, const float* __restrict__ rbuf,
          u16* __restrict__ OH)
{
    const int h = blockIdx.y;
    const int q0 = blockIdx.x * 64;
    const int tid = threadIdx.x, w = tid >> 6, l = tid & 63;
    const int lr = l & 15, lg = l >> 4;
    const int q = q0 + w * 16 + lr;

    float* urow = u + (size_t)h * (NTOK * NTOK) + (size_t)q * NTOK;
    const float* mh = mbuf + h * NTOK;
    const float* rh = rbuf + h * NTOK;
    const u16* Vh = VhT + (size_t)h * (DHEAD * NTOK);

    f32x4 acc[4] = {};
    for (int kb = 0; kb < NTOK; kb += 32) {
        int kk = kb + lg * 8;
        float4 x0 = *(float4*)(urow + kk);
        float4 x1 = *(float4*)(urow + kk + 4);
        float4 ma = *(const float4*)(mh + kk);
        float4 mb = *(const float4*)(mh + kk + 4);
        float4 ra = *(const float4*)(rh + kk);
        float4 rb = *(const float4*)(rh + kk + 4);
        float p0 = __expf(x0.x - ma.x) * ra.x;
        float p1 = __expf(x0.y - ma.y) * ra.y;
        float p2 = __expf(x0.z - ma.z) * ra.z;
        float p3 = __expf(x0.w - ma.w) * ra.w;
        float p4 = __expf(x1.x - mb.x) * rb.x;
        float p5 = __expf(x1.y - mb.y) * rb.y;
        float p6 = __expf(x1.z - mb.z) * rb.z;
        float p7 = __expf(x1.w - mb.w) * rb.w;
        *(float4*)(urow + kk)     = make_float4(p0, p1, p2, p3);
        *(float4*)(urow + kk + 4) = make_float4(p4, p5, p6, p7);
        bf16x8 a;
        a[0] = (short)f2bf(p0); a[1] = (short)f2bf(p1);
        a[2] = (short)f2bf(p2); a[3] = (short)f2bf(p3);
        a[4] = (short)f2bf(p4); a[5] = (short)f2bf(p5);
        a[6] = (short)f2bf(p6); a[7] = (short)f2bf(p7);
        #pragma unroll
        for (int fn = 0; fn < 4; fn++) {
            bf16x8 b = *(const bf16x8*)(Vh + (size_t)(fn * 16 + lr) * NTOK + kk);
            acc[fn] = __builtin_amdgcn_mfma_f32_16x16x32_bf16(a, b, acc[fn], 0, 0, 0);
        }
    }
    #pragma unroll
    for (int fn = 0; fn < 4; fn++)
        #pragma unroll
        for (int i = 0; i < 4; i++) {
            int row = q0 + w * 16 + lg * 4 + i;
            OH[(size_t)h * (NTOK * DHEAD) + (size_t)row * DHEAD + fn * 16 + lr] =
                f2bf(acc[fn][i]);
        }
}

extern "C" void kernel_launch(void* const* d_in, const int* in_sizes, int n_in,
                              void* d_out, int out_size, void* d_ws, size_t ws_size,
                              hipStream_t stream)
{
    const float* q  = (const float*)d_in[0];
    const float* k  = (const float*)d_in[1];
    const float* v  = (const float*)d_in[2];
    const float* Wq = (const float*)d_in[3];
    const float* bq = (const float*)d_in[4];
    const float* Wk = (const float*)d_in[5];
    const float* bk = (const float*)d_in[6];
    const float* Wv = (const float*)d_in[7];
    const float* bv = (const float*)d_in[8];
    const float* Wo = (const float*)d_in[9];
    const float* bo = (const float*)d_in[10];

    float* attn = (float*)d_out;                       // [16][2048][2048] fp32 (also scratch for u)
    float* outp = (float*)d_out + (size_t)ATTN_ELEMS;  // [2048][1024] fp32

    char* ws = (char*)d_ws;
    u16*   Qb   = (u16*)(ws);                          // [2048][1024] bf16
    u16*   Kb   = (u16*)(ws + (4u  << 20));
    u16*   Vb   = (u16*)(ws + (8u  << 20));
    u16*   VhT  = (u16*)(ws + (12u << 20));            // [16][64][2048] bf16
    u16*   OH   = (u16*)(ws + (16u << 20));            // [16][2048][64] bf16 == [2048][1024]
    float* mbuf = (float*)(ws + (20u << 20));          // [16][2048]
    float* rbuf = (float*)(ws + (20u << 20) + (1u << 18));
    float* pm   = (float*)(ws + (21u << 20));          // [8][16][2048]
    float* pl   = (float*)(ws + (22u << 20));

    // 1) QKV projections (fused via grid.z)
    GemmArgs g1{};
    g1.A[0] = q;  g1.A[1] = k;  g1.A[2] = v;
    g1.W[0] = Wq; g1.W[1] = Wk; g1.W[2] = Wv;
    g1.bias[0] = bq; g1.bias[1] = bk; g1.bias[2] = bv;
    g1.C[0] = Qb; g1.C[1] = Kb; g1.C[2] = Vb;
    gemm_bias_k<true, false><<<dim3(8, 16, 3), 256, 0, stream>>>(g1, NTOK, DMODEL, DMODEL);

    // 2) V transpose per head for MFMA B-operand
    transpose_v_k<<<dim3(32, NHEAD), 256, 0, stream>>>(Vb, VhT);

    // 3) scores u = QK^T / 8 into d_out attn region
    scores_k<<<dim3(16, 16, NHEAD), 256, 0, stream>>>(Qb, Kb, attn);

    // 4/5) column softmax stats (softmax over QUERY axis)
    colpart_k<<<dim3(8, 8, NHEAD), 256, 0, stream>>>(attn, pm, pl);
    colreduce_k<<<dim3(8, NHEAD), 256, 0, stream>>>(pm, pl, mbuf, rbuf);

    // 6) normalize in place + PV
    pv_k<<<dim3(32, NHEAD), 256, 0, stream>>>(attn, VhT, mbuf, rbuf, OH);

    // 7) out = OH_flat @ Wo + bo
    GemmArgs g2{};
    g2.A[0] = OH; g2.W[0] = Wo; g2.bias[0] = bo; g2.C[0] = outp;
    gemm_bias_k<false, true><<<dim3(8, 16, 1), 256, 0, stream>>>(g2, NTOK, DMODEL, DMODEL);
}

// Round 2
// 507.763 us; speedup vs baseline: 1.4070x; 1.4070x over previous
//
#include <hip/hip_runtime.h>

using u16 = unsigned short;
using u32 = unsigned int;
typedef short bf16x8 __attribute__((ext_vector_type(8)));
typedef float f32x4 __attribute__((ext_vector_type(4)));

#define NTOK 2048
#define DMODEL 1024
#define NHEAD 16
#define DHEAD 64
#define ATTN_ELEMS (NHEAD * NTOK * NTOK)  // 67108864

__device__ __forceinline__ u16 f2bf(float f) {
    union { float f; unsigned u; } v; v.f = f;
    unsigned r = v.u + 0x7fffu + ((v.u >> 16) & 1u);
    return (u16)(r >> 16);
}
__device__ __forceinline__ u32 pack2(float a, float b) {
    return (u32)f2bf(a) | ((u32)f2bf(b) << 16);
}

// ---------------------------------------------------------------------------
// W [K][N] f32  ->  WT [N][K] bf16   (64x64 tiles via LDS)
// ---------------------------------------------------------------------------
struct WArgs { const float* src[4]; u16* dst[4]; };

__global__ __launch_bounds__(256)
void convt_w_k(WArgs wa)
{
    __shared__ float tile[64][65];
    const float* W  = wa.src[blockIdx.z];
    u16*         WT = wa.dst[blockIdx.z];
    const int k0 = blockIdx.x * 64, n0 = blockIdx.y * 64;
    const int t = threadIdx.x;
    {
        const int r = t >> 2, c = (t & 3) * 16;
        #pragma unroll
        for (int j = 0; j < 4; j++) {
            float4 f = *(const float4*)(W + (size_t)(k0 + r) * DMODEL + n0 + c + j * 4);
            tile[r][c + j * 4 + 0] = f.x;
            tile[r][c + j * 4 + 1] = f.y;
            tile[r][c + j * 4 + 2] = f.z;
            tile[r][c + j * 4 + 3] = f.w;
        }
    }
    __syncthreads();
    {
        const int n = t >> 2, kc = (t & 3) * 16;
        u16 o[16];
        #pragma unroll
        for (int j = 0; j < 16; j++) o[j] = f2bf(tile[kc + j][n]);
        u16* dst = WT + (size_t)(n0 + n) * DMODEL + k0 + kc;
        *(bf16x8*)dst       = *(bf16x8*)&o[0];
        *(bf16x8*)(dst + 8) = *(bf16x8*)&o[8];
    }
}

// ---------------------------------------------------------------------------
// C[M,N] = A[M,K] @ WT[N,K]^T + bias.  128x128 tile, BK=32, 256 thr (2x2 waves)
// ---------------------------------------------------------------------------
struct GemmArgs {
    const void* A[3];
    const u16*  WT[3];
    const float* bias[3];
    void* C[3];
};

template <bool A_F32, bool OUT_F32>
__global__ __launch_bounds__(256)
void gemm_bias_k(GemmArgs ga, int M, int N, int K)
{
    __shared__ u16 As[128][40];
    __shared__ u16 Bs[128][40];
    const void* Ap   = ga.A[blockIdx.z];
    const u16*  WT   = ga.WT[blockIdx.z];
    const float* bias = ga.bias[blockIdx.z];
    void*       Cp   = ga.C[blockIdx.z];

    const int tid = threadIdx.x;
    const int m0 = blockIdx.y * 128;
    const int n0 = blockIdx.x * 128;
    const int w = tid >> 6, l = tid & 63;
    const int wm = (w >> 1) * 64, wn = (w & 1) * 64;
    const int lr = l & 15, lg = l >> 4;

    f32x4 acc[4][4] = {};

    for (int kb = 0; kb < K; kb += 32) {
        if (A_F32) {
            const float* A = (const float*)Ap;
            #pragma unroll
            for (int i = 0; i < 4; i++) {
                int idx = tid + i * 256;
                int row = idx >> 3, kc = (idx & 7) * 4;
                float4 f = *(const float4*)(A + (size_t)(m0 + row) * K + kb + kc);
                As[row][kc + 0] = f2bf(f.x);
                As[row][kc + 1] = f2bf(f.y);
                As[row][kc + 2] = f2bf(f.z);
                As[row][kc + 3] = f2bf(f.w);
            }
        } else {
            const u16* A = (const u16*)Ap;
            #pragma unroll
            for (int i = 0; i < 2; i++) {
                int idx = tid + i * 256;
                int row = idx >> 2, kc = (idx & 3) * 8;
                *(bf16x8*)&As[row][kc] =
                    *(const bf16x8*)(A + (size_t)(m0 + row) * K + kb + kc);
            }
        }
        #pragma unroll
        for (int i = 0; i < 2; i++) {
            int idx = tid + i * 256;
            int row = idx >> 2, kc = (idx & 3) * 8;
            *(bf16x8*)&Bs[row][kc] =
                *(const bf16x8*)(WT + (size_t)(n0 + row) * K + kb + kc);
        }
        __syncthreads();

        bf16x8 a[4], b[4];
        #pragma unroll
        for (int fm = 0; fm < 4; fm++) a[fm] = *(const bf16x8*)&As[wm + fm * 16 + lr][lg * 8];
        #pragma unroll
        for (int fn = 0; fn < 4; fn++) b[fn] = *(const bf16x8*)&Bs[wn + fn * 16 + lr][lg * 8];
        #pragma unroll
        for (int fm = 0; fm < 4; fm++)
            #pragma unroll
            for (int fn = 0; fn < 4; fn++)
                acc[fm][fn] = __builtin_amdgcn_mfma_f32_16x16x32_bf16(a[fm], b[fn], acc[fm][fn], 0, 0, 0);
        __syncthreads();
    }

    #pragma unroll
    for (int fm = 0; fm < 4; fm++)
        #pragma unroll
        for (int fn = 0; fn < 4; fn++) {
            int col = n0 + wn + fn * 16 + lr;
            float bv = bias[col];
            #pragma unroll
            for (int i = 0; i < 4; i++) {
                int row = m0 + wm + fm * 16 + lg * 4 + i;
                float v = acc[fm][fn][i] + bv;
                if (OUT_F32) ((float*)Cp)[(size_t)row * N + col] = v;
                else         ((u16*)Cp)[(size_t)row * N + col] = f2bf(v);
            }
        }
}

// ---------------------------------------------------------------------------
// VhT[h][d][n] = Vb[n][h*64+d]   (bf16)
// ---------------------------------------------------------------------------
__global__ __launch_bounds__(256)
void transpose_v_k(const u16* __restrict__ Vb, u16* __restrict__ VhT)
{
    __shared__ u16 tile[64][65];
    const int h = blockIdx.y;
    const int nb = blockIdx.x * 64;
    const int t = threadIdx.x;
    #pragma unroll
    for (int i = 0; i < 16; i++) {
        int idx = i * 256 + t;
        int nl = idx >> 6, d = idx & 63;
        tile[nl][d] = Vb[(size_t)(nb + nl) * DMODEL + h * 64 + d];
    }
    __syncthreads();
    #pragma unroll
    for (int i = 0; i < 16; i++) {
        int idx = i * 256 + t;
        int d = idx >> 6, nl = idx & 63;
        VhT[(size_t)h * (DHEAD * NTOK) + (size_t)d * NTOK + nb + nl] = tile[nl][d];
    }
}

// ---------------------------------------------------------------------------
// stats: r[h][k] = 1 / sum_q exp(u[h][q][k]/8)   (no-max softmax, fp32 safe)
// swapped QK^T: mfma(A=K rows, B=Q rows) -> C[k][q]
// grid (16 ktiles, 16 heads), 512 thr (8 waves x 16 q each / iter)
// ---------------------------------------------------------------------------
__global__ __launch_bounds__(512, 2)
void stats_k(const u16* __restrict__ Qb, const u16* __restrict__ Kb,
             float* __restrict__ rbuf)
{
    __shared__ float sacc[8][128];
    const int h = blockIdx.y, k0 = blockIdx.x * 128;
    const int tid = threadIdx.x, w = tid >> 6, l = tid & 63;
    const int lr = l & 15, lg = l >> 4;
    const u16* Qh = Qb + h * 64;
    const u16* Kh = Kb + h * 64;

    bf16x8 ak[8][2];
    #pragma unroll
    for (int fm = 0; fm < 8; fm++)
        #pragma unroll
        for (int ds = 0; ds < 2; ds++)
            ak[fm][ds] = *(const bf16x8*)(Kh + (size_t)(k0 + fm * 16 + lr) * DMODEL + ds * 32 + lg * 8);

    float s[8][4] = {};
    for (int qt = 0; qt < 16; qt++) {
        const int q = qt * 128 + w * 16 + lr;
        bf16x8 b0 = *(const bf16x8*)(Qh + (size_t)q * DMODEL + lg * 8);
        bf16x8 b1 = *(const bf16x8*)(Qh + (size_t)q * DMODEL + 32 + lg * 8);
        #pragma unroll
        for (int fm = 0; fm < 8; fm++) {
            f32x4 u = {};
            u = __builtin_amdgcn_mfma_f32_16x16x32_bf16(ak[fm][0], b0, u, 0, 0, 0);
            u = __builtin_amdgcn_mfma_f32_16x16x32_bf16(ak[fm][1], b1, u, 0, 0, 0);
            #pragma unroll
            for (int i = 0; i < 4; i++) s[fm][i] += __expf(u[i] * 0.125f);
        }
    }
    // reduce over the 16 q-lanes (lr)
    #pragma unroll
    for (int off = 1; off < 16; off <<= 1)
        #pragma unroll
        for (int fm = 0; fm < 8; fm++)
            #pragma unroll
            for (int i = 0; i < 4; i++)
                s[fm][i] += __shfl_xor(s[fm][i], off, 64);
    if (lr == 0) {
        #pragma unroll
        for (int fm = 0; fm < 8; fm++)
            #pragma unroll
            for (int i = 0; i < 4; i++)
                sacc[w][fm * 16 + lg * 4 + i] = s[fm][i];
    }
    __syncthreads();
    if (tid < 128) {
        float t = 0.f;
        #pragma unroll
        for (int ww = 0; ww < 8; ww++) t += sacc[ww][tid];
        rbuf[h * NTOK + k0 + tid] = 1.0f / t;
    }
}

// ---------------------------------------------------------------------------
// attn+PV fused: recompute u (swapped), attn = exp(u/8)*r[k] -> f32 store
// (contiguous dwordx4 per lane), register shfl-repack -> PV MFMA -> OH bf16.
// grid (16 qtiles, 16 heads), 512 thr (8 waves x 16 q rows)
// ---------------------------------------------------------------------------
__global__ __launch_bounds__(512, 2)
void attn_pv_k(const u16* __restrict__ Qb, const u16* __restrict__ Kb,
               const u16* __restrict__ VhT, const float* __restrict__ rbuf,
               float* __restrict__ attn, u16* __restrict__ OH)
{
    const int h = blockIdx.y, q0 = blockIdx.x * 128;
    const int tid = threadIdx.x, w = tid >> 6, l = tid & 63;
    const int lr = l & 15, lg = l >> 4;
    const int qw = q0 + w * 16;
    const u16* Qh = Qb + h * 64;
    const u16* Kh = Kb + h * 64;
    const u16* Vh = VhT + (size_t)h * (DHEAD * NTOK);
    const float* rh = rbuf + h * NTOK;
    float* ah = attn + ((size_t)h << 22);

    bf16x8 bq0 = *(const bf16x8*)(Qh + (size_t)(qw + lr) * DMODEL + lg * 8);
    bf16x8 bq1 = *(const bf16x8*)(Qh + (size_t)(qw + lr) * DMODEL + 32 + lg * 8);

    f32x4 acc[4] = {};
    const int srcA = lr + ((lg & 1) << 5);   // lane holding j0..3 halves
    const int srcB = srcA + 16;              // lane holding j4..7 halves

    for (int kt = 0; kt < 16; kt++) {
        const int kb = kt * 128;
        // --- QK^T (swapped: rows = k, cols = q) ---
        f32x4 u[8];
        #pragma unroll
        for (int fm = 0; fm < 8; fm++) {
            bf16x8 a0 = *(const bf16x8*)(Kh + (size_t)(kb + fm * 16 + lr) * DMODEL + lg * 8);
            bf16x8 a1 = *(const bf16x8*)(Kh + (size_t)(kb + fm * 16 + lr) * DMODEL + 32 + lg * 8);
            f32x4 z = {};
            z = __builtin_amdgcn_mfma_f32_16x16x32_bf16(a0, bq0, z, 0, 0, 0);
            u[fm] = __builtin_amdgcn_mfma_f32_16x16x32_bf16(a1, bq1, z, 0, 0, 0);
        }
        // --- normalize, store attn (f32, 16B contiguous per lane), pack bf16 ---
        u32 plo[8], phi[8];
        #pragma unroll
        for (int fm = 0; fm < 8; fm++) {
            float4 rv = *(const float4*)(rh + kb + fm * 16 + lg * 4);
            float p0 = __expf(u[fm][0] * 0.125f) * rv.x;
            float p1 = __expf(u[fm][1] * 0.125f) * rv.y;
            float p2 = __expf(u[fm][2] * 0.125f) * rv.z;
            float p3 = __expf(u[fm][3] * 0.125f) * rv.w;
            *(float4*)(ah + (size_t)(qw + lr) * NTOK + kb + fm * 16 + lg * 4) =
                make_float4(p0, p1, p2, p3);
            plo[fm] = pack2(p0, p1);
            phi[fm] = pack2(p2, p3);
        }
        // --- register repack (C[k][q] frags -> PV A frags) + PV MFMA ---
        #pragma unroll
        for (int ks = 0; ks < 4; ks++) {
            u32 e, o, w0, w1, w2, w3;
            e = __shfl(plo[ks * 2], srcA, 64); o = __shfl(plo[ks * 2 + 1], srcA, 64);
            w0 = (lg & 2) ? o : e;
            e = __shfl(phi[ks * 2], srcA, 64); o = __shfl(phi[ks * 2 + 1], srcA, 64);
            w1 = (lg & 2) ? o : e;
            e = __shfl(plo[ks * 2], srcB, 64); o = __shfl(plo[ks * 2 + 1], srcB, 64);
            w2 = (lg & 2) ? o : e;
            e = __shfl(phi[ks * 2], srcB, 64); o = __shfl(phi[ks * 2 + 1], srcB, 64);
            w3 = (lg & 2) ? o : e;
            union { bf16x8 v; u32 u4[4]; } af;
            af.u4[0] = w0; af.u4[1] = w1; af.u4[2] = w2; af.u4[3] = w3;
            #pragma unroll
            for (int fn = 0; fn < 4; fn++) {
                bf16x8 bv = *(const bf16x8*)(Vh + (size_t)(fn * 16 + lr) * NTOK + kb + ks * 32 + lg * 8);
                acc[fn] = __builtin_amdgcn_mfma_f32_16x16x32_bf16(af.v, bv, acc[fn], 0, 0, 0);
            }
        }
    }
    // --- OH store: rows q = qw + lg*4 + i, cols d = fn*16 + lr ---
    #pragma unroll
    for (int fn = 0; fn < 4; fn++)
        #pragma unroll
        for (int i = 0; i < 4; i++)
            OH[(size_t)h * (NTOK * DHEAD) + (size_t)(qw + lg * 4 + i) * DHEAD + fn * 16 + lr] =
                f2bf(acc[fn][i]);
}

// ---------------------------------------------------------------------------
extern "C" void kernel_launch(void* const* d_in, const int* in_sizes, int n_in,
                              void* d_out, int out_size, void* d_ws, size_t ws_size,
                              hipStream_t stream)
{
    const float* q  = (const float*)d_in[0];
    const float* k  = (const float*)d_in[1];
    const float* v  = (const float*)d_in[2];
    const float* Wq = (const float*)d_in[3];
    const float* bq = (const float*)d_in[4];
    const float* Wk = (const float*)d_in[5];
    const float* bk = (const float*)d_in[6];
    const float* Wv = (const float*)d_in[7];
    const float* bv = (const float*)d_in[8];
    const float* Wo = (const float*)d_in[9];
    const float* bo = (const float*)d_in[10];

    float* attn = (float*)d_out;                       // [16][2048][2048] f32
    float* outp = (float*)d_out + (size_t)ATTN_ELEMS;  // [2048][1024] f32

    // scratch living in the attn region (dead before attn_pv_k writes it)
    char* ob = (char*)d_out;
    u16* Vb  = (u16*)(ob);                 // [2048][1024] bf16 (4MB)
    u16* WTq = (u16*)(ob + (4u << 20));    // [1024][1024] bf16 (2MB each)
    u16* WTk = (u16*)(ob + (6u << 20));
    u16* WTv = (u16*)(ob + (8u << 20));

    // persistent scratch in d_ws (~18.2 MB)
    char* ws = (char*)d_ws;
    u16*   Qb   = (u16*)(ws);                          // 4MB
    u16*   Kb   = (u16*)(ws + (4u  << 20));            // 4MB
    u16*   VhT  = (u16*)(ws + (8u  << 20));            // 4MB [16][64][2048]
    u16*   OH   = (u16*)(ws + (12u << 20));            // 4MB [16][2048][64]
    u16*   WTo  = (u16*)(ws + (16u << 20));            // 2MB
    float* rbuf = (float*)(ws + (18u << 20));          // 128KB [16][2048]

    // 1) W -> WT bf16 (all four)
    WArgs wa{};
    wa.src[0] = Wq; wa.src[1] = Wk; wa.src[2] = Wv; wa.src[3] = Wo;
    wa.dst[0] = WTq; wa.dst[1] = WTk; wa.dst[2] = WTv; wa.dst[3] = WTo;
    convt_w_k<<<dim3(16, 16, 4), 256, 0, stream>>>(wa);

    // 2) QKV projections
    GemmArgs g1{};
    g1.A[0] = q;  g1.A[1] = k;  g1.A[2] = v;
    g1.WT[0] = WTq; g1.WT[1] = WTk; g1.WT[2] = WTv;
    g1.bias[0] = bq; g1.bias[1] = bk; g1.bias[2] = bv;
    g1.C[0] = Qb; g1.C[1] = Kb; g1.C[2] = Vb;
    gemm_bias_k<true, false><<<dim3(8, 16, 3), 256, 0, stream>>>(g1, NTOK, DMODEL, DMODEL);

    // 3) V transpose per head
    transpose_v_k<<<dim3(32, NHEAD), 256, 0, stream>>>(Vb, VhT);

    // 4) column-softmax denominators (recompute QK^T, no u materialization)
    stats_k<<<dim3(16, NHEAD), 512, 0, stream>>>(Qb, Kb, rbuf);

    // 5) attn write + PV fused (recompute QK^T swapped)
    attn_pv_k<<<dim3(16, NHEAD), 512, 0, stream>>>(Qb, Kb, VhT, rbuf, attn, OH);

    // 6) out = OH_flat @ WTo^T + bo
    GemmArgs g2{};
    g2.A[0] = OH; g2.WT[0] = WTo; g2.bias[0] = bo; g2.C[0] = outp;
    gemm_bias_k<false, true><<<dim3(8, 16, 1), 256, 0, stream>>>(g2, NTOK, DMODEL, DMODEL);
}